// Round 1
// baseline (2190.294 us; speedup 1.0000x reference)
//
#include <hip/hip_runtime.h>
#include <hip/hip_bf16.h>
#include <math.h>

#define BS 32
#define QN 256
#define TN 128
#define NCLS 2048
#define NTGT (BS * TN)  // 4096

// ---------------------------------------------------------------------------
// Detect whether agent_mask is stored as 1-byte bools or 4-byte int32.
// If int32: every byte at offset %4 != 0 over the first BS*QN bytes is zero
// (values are 0/1). If bool: ~3/8 of those bytes are 1 -> flag = 1.
// ---------------------------------------------------------------------------
__global__ void detect_mask_layout(const unsigned char* __restrict__ m, int* flag) {
    __shared__ int found;
    if (threadIdx.x == 0) found = 0;
    __syncthreads();
    int local = 0;
    for (int i = threadIdx.x; i < BS * QN; i += blockDim.x) {
        if ((i & 3) != 0 && m[i] != 0) local = 1;
    }
    if (local) atomicOr(&found, 1);
    __syncthreads();
    if (threadIdx.x == 0) *flag = found;  // 1 = byte layout, 0 = int32 layout
}

// ---------------------------------------------------------------------------
// C[b,q,jj] = -(softmax(logits[b,q,:])[labels_flat[jj]]), zeroed if masked.
// One block per (b,q); 256 threads.
// ---------------------------------------------------------------------------
__global__ __launch_bounds__(256) void compute_C_kernel(
    const float* __restrict__ logits, const int* __restrict__ labels,
    const unsigned char* __restrict__ mask_b, const int* __restrict__ use_bg,
    const int* __restrict__ layout_flag, float* __restrict__ C) {
    __shared__ float prob_sh[NCLS];
    __shared__ int lab_sh[NTGT];
    __shared__ float red[4];

    const int tid = threadIdx.x;
    const int bq = blockIdx.x;           // b*QN + q
    const float* row = logits + (size_t)bq * NCLS;

    // stage labels (flattened over all batches, per reference)
    for (int k = tid; k < NTGT; k += 256) lab_sh[k] = labels[k];

    // load 8 elems/thread, strided for coalescing
    float x[8];
    float m = -INFINITY;
#pragma unroll
    for (int k = 0; k < 8; k++) {
        x[k] = row[tid + k * 256];
        m = fmaxf(m, x[k]);
    }
#pragma unroll
    for (int off = 32; off >= 1; off >>= 1) m = fmaxf(m, __shfl_xor(m, off));
    if ((tid & 63) == 0) red[tid >> 6] = m;
    __syncthreads();
    m = fmaxf(fmaxf(red[0], red[1]), fmaxf(red[2], red[3]));
    __syncthreads();  // red is reused below

    float e[8];
    float s = 0.f;
#pragma unroll
    for (int k = 0; k < 8; k++) {
        e[k] = expf(x[k] - m);
        s += e[k];
    }
#pragma unroll
    for (int off = 32; off >= 1; off >>= 1) s += __shfl_xor(s, off);
    if ((tid & 63) == 0) red[tid >> 6] = s;
    __syncthreads();
    s = ((red[0] + red[1]) + red[2]) + red[3];

    // per-class divide (matches reference: probs = e / sum, then gather)
#pragma unroll
    for (int k = 0; k < 8; k++) prob_sh[tid + k * 256] = e[k] / s;

    const int ub = *use_bg;
    int am;
    if (*layout_flag)
        am = mask_b[bq];
    else
        am = ((const int*)mask_b)[bq];
    const bool zero_row = (ub == 0) && (am == 0);
    __syncthreads();

    float* Crow = C + (size_t)bq * NTGT;
#pragma unroll
    for (int k = 0; k < 16; k++) {
        const int jj = tid + k * 256;
        Crow[jj] = zero_row ? 0.0f : -prob_sh[lab_sh[jj]];
    }
}

// ---------------------------------------------------------------------------
// Jonker-Volgenant shortest augmenting path, exact replica of the reference
// _lsa() on the TRANSPOSED problem: nr = TN = 128 rows (targets),
// nc = QN = 256 cols (queries). cost(i,j) = C[(b*QN + j)*NTGT + b*TN + i].
// One block per batch, one thread per column. Thread 0 does scalar decisions.
// ---------------------------------------------------------------------------
__global__ __launch_bounds__(256) void lsa_kernel(const float* __restrict__ C,
                                                  float* __restrict__ rows_out,
                                                  float* __restrict__ cols_out) {
    const int b = blockIdx.x;
    const int tid = threadIdx.x;

    __shared__ double u_sh[TN];
    __shared__ double v_sh[QN];
    __shared__ double d_sh[QN];
    __shared__ int path_sh[QN];
    __shared__ int row4col_sh[QN];
    __shared__ int col4row_sh[TN];
    __shared__ int SC_sh[QN];
    __shared__ int SR_sh[TN];
    __shared__ double wv[4];
    __shared__ int wi[4];
    __shared__ double minVal_sh;
    __shared__ int i_sh, sink_sh;

    v_sh[tid] = 0.0;
    row4col_sh[tid] = -1;
    path_sh[tid] = -1;
    if (tid < TN) {
        u_sh[tid] = 0.0;
        col4row_sh[tid] = -1;
    }
    __syncthreads();

    // this thread's column base: Cb[i] = cost(i, tid)
    const float* Cb = C + (size_t)(b * QN + tid) * NTGT + b * TN;

    for (int cur = 0; cur < TN; cur++) {
        d_sh[tid] = INFINITY;
        SC_sh[tid] = 0;
        if (tid < TN) SR_sh[tid] = 0;
        if (tid == 0) {
            i_sh = cur;
            minVal_sh = 0.0;
            sink_sh = -1;
        }
        __syncthreads();

        while (true) {
            const int i = i_sh;
            const double minV = minVal_sh;
            if (tid == 0) SR_sh[i] = 1;

            if (!SC_sh[tid]) {
                // evaluation order matches numpy: ((minVal + cost) - u[i]) - v[j]
                const double r = ((minV + (double)Cb[i]) - u_sh[i]) - v_sh[tid];
                if (r < d_sh[tid]) {
                    d_sh[tid] = r;
                    path_sh[tid] = i;
                }
            }

            // argmin over remaining columns, first-min (smallest index) on ties
            double key = SC_sh[tid] ? INFINITY : d_sh[tid];
            int kidx = tid;
#pragma unroll
            for (int off = 32; off >= 1; off >>= 1) {
                const double ov = __shfl_xor(key, off);
                const int oi = __shfl_xor(kidx, off);
                if (ov < key || (ov == key && oi < kidx)) {
                    key = ov;
                    kidx = oi;
                }
            }
            if ((tid & 63) == 0) {
                wv[tid >> 6] = key;
                wi[tid >> 6] = kidx;
            }
            __syncthreads();

            if (tid == 0) {
                double bv = wv[0];
                int bi = wi[0];
#pragma unroll
                for (int w = 1; w < 4; w++) {
                    if (wv[w] < bv || (wv[w] == bv && wi[w] < bi)) {
                        bv = wv[w];
                        bi = wi[w];
                    }
                }
                minVal_sh = bv;  // == d_sh[bi]
                SC_sh[bi] = 1;
                const int r4 = row4col_sh[bi];
                if (r4 < 0)
                    sink_sh = bi;
                else
                    i_sh = r4;
            }
            __syncthreads();
            if (sink_sh >= 0) break;
        }

        // dual updates (exactly scipy _lsap_body)
        const double minV = minVal_sh;
        if (tid < TN) {
            if (tid == cur)
                u_sh[tid] += minV;
            else if (SR_sh[tid])
                u_sh[tid] += minV - d_sh[col4row_sh[tid]];
        }
        if (SC_sh[tid]) v_sh[tid] -= minV - d_sh[tid];
        __syncthreads();

        // augment along shortest path (serial, thread 0)
        if (tid == 0) {
            int j = sink_sh;
            while (true) {
                const int i = path_sh[j];
                row4col_sh[j] = i;
                const int nj = col4row_sh[i];
                col4row_sh[i] = j;
                j = nj;
                if (i == cur) break;
            }
        }
        __syncthreads();
    }

    // transposed output: order = argsort(col4row) (values distinct),
    // rows = col4row[order], cols = order. rank via counting.
    if (tid < TN) {
        const int myv = col4row_sh[tid];
        int rank = 0;
        for (int t = 0; t < TN; t++) rank += (col4row_sh[t] < myv) ? 1 : 0;
        rows_out[b * TN + rank] = (float)myv;
        cols_out[b * TN + rank] = (float)tid;
    }
}

extern "C" void kernel_launch(void* const* d_in, const int* in_sizes, int n_in,
                              void* d_out, int out_size, void* d_ws, size_t ws_size,
                              hipStream_t stream) {
    const float* logits = (const float*)d_in[0];          // [32,256,2048] f32
    const int* labels = (const int*)d_in[1];              // [32,128] i32
    const unsigned char* mask_b = (const unsigned char*)d_in[2];  // [32,256] bool/i32
    const int* use_bg = (const int*)d_in[3];              // scalar (0)

    float* C = (float*)d_out;                              // 32*256*4096
    float* rows_out = C + (size_t)BS * QN * NTGT;          // 32*128
    float* cols_out = rows_out + BS * TN;                  // 32*128
    int* flag = (int*)d_ws;

    detect_mask_layout<<<1, 256, 0, stream>>>(mask_b, flag);
    compute_C_kernel<<<BS * QN, 256, 0, stream>>>(logits, labels, mask_b, use_bg, flag, C);
    lsa_kernel<<<BS, 256, 0, stream>>>(C, rows_out, cols_out);
}

// Round 2
// 2042.888 us; speedup vs baseline: 1.0722x; 1.0722x over previous
//
#include <hip/hip_runtime.h>
#include <hip/hip_bf16.h>
#include <math.h>

#define BS 32
#define QN 256
#define TN 128
#define NCLS 2048
#define NTGT (BS * TN)  // 4096

// ---------------------------------------------------------------------------
// Detect whether agent_mask is stored as 1-byte bools or 4-byte int32.
// ---------------------------------------------------------------------------
__global__ void detect_mask_layout(const unsigned char* __restrict__ m, int* flag) {
    __shared__ int found;
    if (threadIdx.x == 0) found = 0;
    __syncthreads();
    int local = 0;
    for (int i = threadIdx.x; i < BS * QN; i += blockDim.x) {
        if ((i & 3) != 0 && m[i] != 0) local = 1;
    }
    if (local) atomicOr(&found, 1);
    __syncthreads();
    if (threadIdx.x == 0) *flag = found;  // 1 = byte layout, 0 = int32 layout
}

// ---------------------------------------------------------------------------
// C[b,q,jj] = -(softmax(logits[b,q,:])[labels_flat[jj]]), zeroed if masked.
// One block per (b,q); 256 threads.
// ---------------------------------------------------------------------------
__global__ __launch_bounds__(256) void compute_C_kernel(
    const float* __restrict__ logits, const int* __restrict__ labels,
    const unsigned char* __restrict__ mask_b, const int* __restrict__ use_bg,
    const int* __restrict__ layout_flag, float* __restrict__ C) {
    __shared__ float prob_sh[NCLS];
    __shared__ int lab_sh[NTGT];
    __shared__ float red[4];

    const int tid = threadIdx.x;
    const int bq = blockIdx.x;  // b*QN + q
    const float* row = logits + (size_t)bq * NCLS;

    for (int k = tid; k < NTGT; k += 256) lab_sh[k] = labels[k];

    float x[8];
    float m = -INFINITY;
#pragma unroll
    for (int k = 0; k < 8; k++) {
        x[k] = row[tid + k * 256];
        m = fmaxf(m, x[k]);
    }
#pragma unroll
    for (int off = 32; off >= 1; off >>= 1) m = fmaxf(m, __shfl_xor(m, off));
    if ((tid & 63) == 0) red[tid >> 6] = m;
    __syncthreads();
    m = fmaxf(fmaxf(red[0], red[1]), fmaxf(red[2], red[3]));
    __syncthreads();

    float e[8];
    float s = 0.f;
#pragma unroll
    for (int k = 0; k < 8; k++) {
        e[k] = expf(x[k] - m);
        s += e[k];
    }
#pragma unroll
    for (int off = 32; off >= 1; off >>= 1) s += __shfl_xor(s, off);
    if ((tid & 63) == 0) red[tid >> 6] = s;
    __syncthreads();
    s = ((red[0] + red[1]) + red[2]) + red[3];

#pragma unroll
    for (int k = 0; k < 8; k++) prob_sh[tid + k * 256] = e[k] / s;

    const int ub = *use_bg;
    int am;
    if (*layout_flag)
        am = mask_b[bq];
    else
        am = ((const int*)mask_b)[bq];
    const bool zero_row = (ub == 0) && (am == 0);
    __syncthreads();

    float* Crow = C + (size_t)bq * NTGT;
#pragma unroll
    for (int k = 0; k < 16; k++) {
        const int jj = tid + k * 256;
        Crow[jj] = zero_row ? 0.0f : -prob_sh[lab_sh[jj]];
    }
}

// ---------------------------------------------------------------------------
// Transpose the block-diagonal part of C into CT[b][i][q] (i=target, q=query)
// so the lsa inner loop can read cost rows coalesced.
// Block = (batch, q-tile of 64). LDS tile transpose, conflict-free (stride 65).
// ---------------------------------------------------------------------------
__global__ __launch_bounds__(256) void transpose_kernel(const float* __restrict__ C,
                                                        float* __restrict__ CT) {
    __shared__ float tile[TN][65];  // [i][q_local], 64 q per block
    const int b = blockIdx.x;
    const int q0 = blockIdx.y * 64;
    const int tid = threadIdx.x;

    // read: (q_local, i) with i fastest -> contiguous 128-float runs
    const float* src = C + (size_t)(b * QN + q0) * NTGT + b * TN;
#pragma unroll
    for (int it = 0; it < 32; it++) {
        const int idx = tid + it * 256;        // 0..8191
        const int ql = idx >> 7;               // 0..63
        const int i = idx & 127;               // 0..127
        tile[i][ql] = src[(size_t)ql * NTGT + i];
    }
    __syncthreads();
    // write: (i, q_local) with q fastest -> contiguous 64-float runs
    float* dst = CT + (size_t)b * TN * QN + q0;
#pragma unroll
    for (int it = 0; it < 32; it++) {
        const int idx = tid + it * 256;
        const int i = idx >> 6;                // 0..127
        const int ql = idx & 63;               // 0..63
        dst[(size_t)i * QN + ql] = tile[i][ql];
    }
}

// ---------------------------------------------------------------------------
// Jonker-Volgenant, exact replica of reference _lsa() on the transposed
// problem (nr=TN=128 rows, nc=QN=256 cols). ONE WAVE per batch; each lane
// owns 4 columns (d, v, SC, in registers). No barriers in the Dijkstra
// inner loop: all cross-lane flow is shuffles + LDS arrays written only at
// round boundaries.
// ---------------------------------------------------------------------------
__global__ __launch_bounds__(64) void lsa_kernel(const float* __restrict__ C,
                                                 const float* __restrict__ CT,
                                                 float* __restrict__ rows_out,
                                                 float* __restrict__ cols_out) {
    const int b = blockIdx.x;
    const int lane = threadIdx.x;  // 0..63
    const int j0 = lane * 4;

    __shared__ double u_sh[TN];
    __shared__ double du_sh[TN];     // d[col4row[i]] recorded when row i enters SR
    __shared__ int SRr_sh[TN];
    __shared__ int path_sh[QN];
    __shared__ int row4col_sh[QN];
    __shared__ int col4row_sh[TN];

    u_sh[lane] = 0.0;
    u_sh[lane + 64] = 0.0;
    col4row_sh[lane] = -1;
    col4row_sh[lane + 64] = -1;
#pragma unroll
    for (int t = 0; t < 4; t++) row4col_sh[lane + 64 * t] = -1;

    double v0 = 0.0, v1 = 0.0, v2 = 0.0, v3 = 0.0;

    const float* ctb = CT ? (CT + (size_t)b * TN * QN) : nullptr;
    const float* cb = C + (size_t)b * QN * NTGT + b * TN;  // cost(i,j) = cb[j*NTGT + i]

    __syncthreads();

    for (int cur = 0; cur < TN; cur++) {
        SRr_sh[lane] = 0;
        SRr_sh[lane + 64] = 0;
        double d0 = INFINITY, d1 = INFINITY, d2 = INFINITY, d3 = INFINITY;
        int sc0 = 0, sc1 = 0, sc2 = 0, sc3 = 0;
        __syncthreads();  // B1: SR reset visible before lane0 sets SRr[cur]

        int i = cur;
        double minV = 0.0;
        if (lane == 0) SRr_sh[cur] = 1;
        int sink = -1;
        double key;  // holds final minVal after loop

        while (true) {
            // cost row i, this lane's 4 columns
            double c0, c1, c2, c3;
            if (ctb) {
                const float4 cc = *(const float4*)(ctb + (size_t)i * QN + j0);
                c0 = cc.x; c1 = cc.y; c2 = cc.z; c3 = cc.w;
            } else {
                c0 = cb[(size_t)(j0 + 0) * NTGT + i];
                c1 = cb[(size_t)(j0 + 1) * NTGT + i];
                c2 = cb[(size_t)(j0 + 2) * NTGT + i];
                c3 = cb[(size_t)(j0 + 3) * NTGT + i];
            }
            const double ui = u_sh[i];

            // numpy order: ((minVal + cost) - u[i]) - v[j]; strict r < d
            if (!sc0) { const double r = ((minV + c0) - ui) - v0; if (r < d0) { d0 = r; path_sh[j0 + 0] = i; } }
            if (!sc1) { const double r = ((minV + c1) - ui) - v1; if (r < d1) { d1 = r; path_sh[j0 + 1] = i; } }
            if (!sc2) { const double r = ((minV + c2) - ui) - v2; if (r < d2) { d2 = r; path_sh[j0 + 2] = i; } }
            if (!sc3) { const double r = ((minV + c3) - ui) - v3; if (r < d3) { d3 = r; path_sh[j0 + 3] = i; } }

            // local first-min (strict < keeps smallest index on ties)
            key = INFINITY;
            int kidx = j0;
            if (!sc0 && d0 < key) { key = d0; kidx = j0 + 0; }
            if (!sc1 && d1 < key) { key = d1; kidx = j0 + 1; }
            if (!sc2 && d2 < key) { key = d2; kidx = j0 + 2; }
            if (!sc3 && d3 < key) { key = d3; kidx = j0 + 3; }

            // 64-lane butterfly lexicographic (value, index) min
#pragma unroll
            for (int off = 32; off >= 1; off >>= 1) {
                const double ov = __shfl_xor(key, off);
                const int oi = __shfl_xor(kidx, off);
                if (ov < key || (ov == key && oi < kidx)) { key = ov; kidx = oi; }
            }
            // all lanes: (key, kidx) = (minVal, selected column j)

            if ((kidx >> 2) == lane) {  // owner marks SC
                const int k = kidx & 3;
                if (k == 0) sc0 = 1;
                else if (k == 1) sc1 = 1;
                else if (k == 2) sc2 = 1;
                else sc3 = 1;
            }

            const int r4 = row4col_sh[kidx];  // uniform broadcast read
            if (r4 < 0) { sink = kidx; break; }
            if (lane == 0) { SRr_sh[r4] = 1; du_sh[r4] = key; }
            i = r4;
            minV = key;
        }

        const double minVF = key;  // final minVal
        __syncthreads();  // B2: du_sh, SRr_sh, path_sh visible

        // dual updates (scipy _lsap_body)
#pragma unroll
        for (int t = 0; t < 2; t++) {
            const int ii = lane + 64 * t;
            if (SRr_sh[ii]) u_sh[ii] += (ii == cur) ? minVF : (minVF - du_sh[ii]);
        }
        if (sc0) v0 -= minVF - d0;
        if (sc1) v1 -= minVF - d1;
        if (sc2) v2 -= minVF - d2;
        if (sc3) v3 -= minVF - d3;

        // augment (lane 0, serial) — touches path/row4col/col4row only
        if (lane == 0) {
            int j = sink;
            while (true) {
                const int pi = path_sh[j];
                row4col_sh[j] = pi;
                const int nj = col4row_sh[pi];
                col4row_sh[pi] = j;
                j = nj;
                if (pi == cur) break;
            }
        }
        __syncthreads();  // B3: u, row4col, col4row visible for next round
    }

    // transposed output: rank by col4row value (values distinct)
#pragma unroll
    for (int t = 0; t < 2; t++) {
        const int ii = lane + 64 * t;
        const int myv = col4row_sh[ii];
        int rank = 0;
        for (int t2 = 0; t2 < TN; t2++) rank += (col4row_sh[t2] < myv) ? 1 : 0;
        rows_out[b * TN + rank] = (float)myv;
        cols_out[b * TN + rank] = (float)ii;
    }
}

extern "C" void kernel_launch(void* const* d_in, const int* in_sizes, int n_in,
                              void* d_out, int out_size, void* d_ws, size_t ws_size,
                              hipStream_t stream) {
    const float* logits = (const float*)d_in[0];                  // [32,256,2048] f32
    const int* labels = (const int*)d_in[1];                      // [32,128] i32
    const unsigned char* mask_b = (const unsigned char*)d_in[2];  // [32,256] bool/i32
    const int* use_bg = (const int*)d_in[3];                      // scalar

    float* C = (float*)d_out;                              // 32*256*4096
    float* rows_out = C + (size_t)BS * QN * NTGT;
    float* cols_out = rows_out + BS * TN;

    int* flag = (int*)d_ws;
    const size_t ct_off = 4096;
    const size_t ct_bytes = (size_t)BS * TN * QN * sizeof(float);  // 4 MB
    const bool useCT = ws_size >= ct_off + ct_bytes;
    float* CT = useCT ? (float*)((char*)d_ws + ct_off) : nullptr;

    detect_mask_layout<<<1, 256, 0, stream>>>(mask_b, flag);
    compute_C_kernel<<<BS * QN, 256, 0, stream>>>(logits, labels, mask_b, use_bg, flag, C);
    if (useCT) {
        dim3 tg(BS, QN / 64);
        transpose_kernel<<<tg, 256, 0, stream>>>(C, CT);
    }
    lsa_kernel<<<BS, 64, 0, stream>>>(C, CT, rows_out, cols_out);
}

// Round 3
// 1757.028 us; speedup vs baseline: 1.2466x; 1.1627x over previous
//
#include <hip/hip_runtime.h>
#include <hip/hip_bf16.h>
#include <math.h>

#define BS 32
#define QN 256
#define TN 128
#define NCLS 2048
#define NTGT (BS * TN)  // 4096

// ---------------------------------------------------------------------------
// Detect whether agent_mask is stored as 1-byte bools or 4-byte int32.
// ---------------------------------------------------------------------------
__global__ void detect_mask_layout(const unsigned char* __restrict__ m, int* flag) {
    __shared__ int found;
    if (threadIdx.x == 0) found = 0;
    __syncthreads();
    int local = 0;
    for (int i = threadIdx.x; i < BS * QN; i += blockDim.x) {
        if ((i & 3) != 0 && m[i] != 0) local = 1;
    }
    if (local) atomicOr(&found, 1);
    __syncthreads();
    if (threadIdx.x == 0) *flag = found;  // 1 = byte layout, 0 = int32 layout
}

// ---------------------------------------------------------------------------
// C[b,q,jj] = -(softmax(logits[b,q,:])[labels_flat[jj]]), zeroed if masked.
// ---------------------------------------------------------------------------
__global__ __launch_bounds__(256) void compute_C_kernel(
    const float* __restrict__ logits, const int* __restrict__ labels,
    const unsigned char* __restrict__ mask_b, const int* __restrict__ use_bg,
    const int* __restrict__ layout_flag, float* __restrict__ C) {
    __shared__ float prob_sh[NCLS];
    __shared__ int lab_sh[NTGT];
    __shared__ float red[4];

    const int tid = threadIdx.x;
    const int bq = blockIdx.x;  // b*QN + q
    const float* row = logits + (size_t)bq * NCLS;

    for (int k = tid; k < NTGT; k += 256) lab_sh[k] = labels[k];

    float x[8];
    float m = -INFINITY;
#pragma unroll
    for (int k = 0; k < 8; k++) {
        x[k] = row[tid + k * 256];
        m = fmaxf(m, x[k]);
    }
#pragma unroll
    for (int off = 32; off >= 1; off >>= 1) m = fmaxf(m, __shfl_xor(m, off));
    if ((tid & 63) == 0) red[tid >> 6] = m;
    __syncthreads();
    m = fmaxf(fmaxf(red[0], red[1]), fmaxf(red[2], red[3]));
    __syncthreads();

    float e[8];
    float s = 0.f;
#pragma unroll
    for (int k = 0; k < 8; k++) {
        e[k] = expf(x[k] - m);
        s += e[k];
    }
#pragma unroll
    for (int off = 32; off >= 1; off >>= 1) s += __shfl_xor(s, off);
    if ((tid & 63) == 0) red[tid >> 6] = s;
    __syncthreads();
    s = ((red[0] + red[1]) + red[2]) + red[3];

#pragma unroll
    for (int k = 0; k < 8; k++) prob_sh[tid + k * 256] = e[k] / s;

    const int ub = *use_bg;
    int am;
    if (*layout_flag)
        am = mask_b[bq];
    else
        am = ((const int*)mask_b)[bq];
    const bool zero_row = (ub == 0) && (am == 0);
    __syncthreads();

    float* Crow = C + (size_t)bq * NTGT;
#pragma unroll
    for (int k = 0; k < 16; k++) {
        const int jj = tid + k * 256;
        Crow[jj] = zero_row ? 0.0f : -prob_sh[lab_sh[jj]];
    }
}

// ---------------------------------------------------------------------------
// Transpose block-diagonal part of C into CT[b][i][q].
// ---------------------------------------------------------------------------
__global__ __launch_bounds__(256) void transpose_kernel(const float* __restrict__ C,
                                                        float* __restrict__ CT) {
    __shared__ float tile[TN][65];
    const int b = blockIdx.x;
    const int q0 = blockIdx.y * 64;
    const int tid = threadIdx.x;

    const float* src = C + (size_t)(b * QN + q0) * NTGT + b * TN;
#pragma unroll
    for (int it = 0; it < 32; it++) {
        const int idx = tid + it * 256;
        const int ql = idx >> 7;
        const int i = idx & 127;
        tile[i][ql] = src[(size_t)ql * NTGT + i];
    }
    __syncthreads();
    float* dst = CT + (size_t)b * TN * QN + q0;
#pragma unroll
    for (int it = 0; it < 32; it++) {
        const int idx = tid + it * 256;
        const int i = idx >> 6;
        const int ql = idx & 63;
        dst[(size_t)i * QN + ql] = tile[i][ql];
    }
}

// ---------------------------------------------------------------------------
// DPP helpers (wave64: 4 rows of 16 lanes).
// ---------------------------------------------------------------------------
template <int CTRL>
__device__ __forceinline__ int dpp_i32(int x) {
    return __builtin_amdgcn_update_dpp(0, x, CTRL, 0xF, 0xF, true);
}
template <int CTRL>
__device__ __forceinline__ double dpp_f64(double x) {
    union { double d; int i[2]; } a, r;
    a.d = x;
    r.i[0] = __builtin_amdgcn_update_dpp(0, a.i[0], CTRL, 0xF, 0xF, true);
    r.i[1] = __builtin_amdgcn_update_dpp(0, a.i[1], CTRL, 0xF, 0xF, true);
    return r.d;
}

#define QUAD_XOR1 0xB1   // quad_perm(1,0,3,2)
#define QUAD_XOR2 0x4E   // quad_perm(2,3,0,1)
#define ROW_ROR4  0x124  // row_ror:4
#define ROW_ROR8  0x128  // row_ror:8

// ---------------------------------------------------------------------------
// Jonker-Volgenant, exact replica of reference _lsa() on the transposed
// problem (nr=TN=128, nc=QN=256). One wave/batch; lane owns 4 columns.
// Cost block staged in LDS (128 KB). Reduce = 4 DPP stages + 2 bpermute
// stages carrying (d, col, row4col[col]); no LDS lookup on the chain.
// ---------------------------------------------------------------------------
__global__ __launch_bounds__(64) void lsa_kernel(const float* __restrict__ C,
                                                 const float* __restrict__ CT,
                                                 float* __restrict__ rows_out,
                                                 float* __restrict__ cols_out) {
    const int b = blockIdx.x;
    const int lane = threadIdx.x;  // 0..63
    const int j0 = lane * 4;

    __shared__ float cost_sh[TN * QN];  // [i][q], 128 KB
    __shared__ double u_sh[TN];
    __shared__ double du_sh[TN];  // d[col4row[i]] recorded when row i enters SR
    __shared__ int SRr_sh[TN];
    __shared__ int path_sh[QN];
    __shared__ int row4col_sh[QN];
    __shared__ int col4row_sh[TN];

    u_sh[lane] = 0.0;
    u_sh[lane + 64] = 0.0;
    col4row_sh[lane] = -1;
    col4row_sh[lane + 64] = -1;
#pragma unroll
    for (int t = 0; t < 4; t++) row4col_sh[lane + 64 * t] = -1;

    double v0 = 0.0, v1 = 0.0, v2 = 0.0, v3 = 0.0;

    const bool lds_cost = (CT != nullptr);
    const float* cb = C + (size_t)b * QN * NTGT + b * TN;  // fallback gather

    if (lds_cost) {
        const float4* src = (const float4*)(CT + (size_t)b * TN * QN);
        float4* dst = (float4*)cost_sh;
#pragma unroll 8
        for (int it = 0; it < TN * QN / 4 / 64; it++) {
            const int idx = it * 64 + lane;
            dst[idx] = src[idx];
        }
    }
    __syncthreads();

    for (int cur = 0; cur < TN; cur++) {
        SRr_sh[lane] = 0;
        SRr_sh[lane + 64] = 0;
        double d0 = INFINITY, d1 = INFINITY, d2 = INFINITY, d3 = INFINITY;
        int sc0 = 0, sc1 = 0, sc2 = 0, sc3 = 0;
        int4 rc = *(const int4*)&row4col_sh[j0];  // row4col for owned columns
        __syncthreads();  // B1
        if (lane == 0) SRr_sh[cur] = 1;

        int i = cur;
        double minV = 0.0;
        int sink;
        double key;

        while (true) {
            // cost row i, this lane's 4 columns
            double c0, c1, c2, c3;
            if (lds_cost) {
                const float4 cc = *(const float4*)(cost_sh + i * QN + j0);
                c0 = cc.x; c1 = cc.y; c2 = cc.z; c3 = cc.w;
            } else {
                c0 = cb[(size_t)(j0 + 0) * NTGT + i];
                c1 = cb[(size_t)(j0 + 1) * NTGT + i];
                c2 = cb[(size_t)(j0 + 2) * NTGT + i];
                c3 = cb[(size_t)(j0 + 3) * NTGT + i];
            }
            const double ui = u_sh[i];

            // numpy order: ((minVal + cost) - u[i]) - v[j]; strict r < d
            if (!sc0) { const double r = ((minV + c0) - ui) - v0; if (r < d0) { d0 = r; path_sh[j0 + 0] = i; } }
            if (!sc1) { const double r = ((minV + c1) - ui) - v1; if (r < d1) { d1 = r; path_sh[j0 + 1] = i; } }
            if (!sc2) { const double r = ((minV + c2) - ui) - v2; if (r < d2) { d2 = r; path_sh[j0 + 2] = i; } }
            if (!sc3) { const double r = ((minV + c3) - ui) - v3; if (r < d3) { d3 = r; path_sh[j0 + 3] = i; } }

            // local first-min among owned columns, carrying row4col
            key = INFINITY;
            int kidx = j0;
            int krc = rc.x;
            if (!sc0 && d0 < key) { key = d0; kidx = j0 + 0; krc = rc.x; }
            if (!sc1 && d1 < key) { key = d1; kidx = j0 + 1; krc = rc.y; }
            if (!sc2 && d2 < key) { key = d2; kidx = j0 + 2; krc = rc.z; }
            if (!sc3 && d3 < key) { key = d3; kidx = j0 + 3; krc = rc.w; }

            // 64-lane reduce: lexicographic (value, index) min, rc rides along.
            // 4 DPP stages (VALU latency) + 2 bpermute stages.
#define DPP_STAGE(CTRL)                                                        \
            {                                                                  \
                const double ov = dpp_f64<CTRL>(key);                          \
                const int oi = dpp_i32<CTRL>(kidx);                            \
                const int orc = dpp_i32<CTRL>(krc);                            \
                if (ov < key || (ov == key && oi < kidx)) {                    \
                    key = ov; kidx = oi; krc = orc;                            \
                }                                                              \
            }
            DPP_STAGE(QUAD_XOR1)
            DPP_STAGE(QUAD_XOR2)
            DPP_STAGE(ROW_ROR4)
            DPP_STAGE(ROW_ROR8)
#undef DPP_STAGE
#pragma unroll
            for (int off = 16; off <= 32; off <<= 1) {
                const double ov = __shfl_xor(key, off);
                const int oi = __shfl_xor(kidx, off);
                const int orc = __shfl_xor(krc, off);
                if (ov < key || (ov == key && oi < kidx)) {
                    key = ov; kidx = oi; krc = orc;
                }
            }
            // all lanes: key = minVal, kidx = selected col j, krc = row4col[j]

            if ((kidx >> 2) == lane) {  // owner marks SC
                const int k = kidx & 3;
                if (k == 0) sc0 = 1;
                else if (k == 1) sc1 = 1;
                else if (k == 2) sc2 = 1;
                else sc3 = 1;
            }

            if (krc < 0) { sink = kidx; break; }
            if (lane == 0) { SRr_sh[krc] = 1; du_sh[krc] = key; }
            i = krc;
            minV = key;
        }

        const double minVF = key;
        __syncthreads();  // B2: du_sh, SRr_sh, path_sh visible

        // dual updates (scipy _lsap_body)
#pragma unroll
        for (int t = 0; t < 2; t++) {
            const int ii = lane + 64 * t;
            if (SRr_sh[ii]) u_sh[ii] += (ii == cur) ? minVF : (minVF - du_sh[ii]);
        }
        if (sc0) v0 -= minVF - d0;
        if (sc1) v1 -= minVF - d1;
        if (sc2) v2 -= minVF - d2;
        if (sc3) v3 -= minVF - d3;

        // augment (lane 0, serial)
        if (lane == 0) {
            int j = sink;
            while (true) {
                const int pi = path_sh[j];
                row4col_sh[j] = pi;
                const int nj = col4row_sh[pi];
                col4row_sh[pi] = j;
                j = nj;
                if (pi == cur) break;
            }
        }
        __syncthreads();  // B3: u, row4col, col4row visible for next round
    }

    // transposed output: rank by col4row value (values distinct)
#pragma unroll
    for (int t = 0; t < 2; t++) {
        const int ii = lane + 64 * t;
        const int myv = col4row_sh[ii];
        int rank = 0;
        for (int t2 = 0; t2 < TN; t2++) rank += (col4row_sh[t2] < myv) ? 1 : 0;
        rows_out[b * TN + rank] = (float)myv;
        cols_out[b * TN + rank] = (float)ii;
    }
}

extern "C" void kernel_launch(void* const* d_in, const int* in_sizes, int n_in,
                              void* d_out, int out_size, void* d_ws, size_t ws_size,
                              hipStream_t stream) {
    const float* logits = (const float*)d_in[0];                  // [32,256,2048] f32
    const int* labels = (const int*)d_in[1];                      // [32,128] i32
    const unsigned char* mask_b = (const unsigned char*)d_in[2];  // [32,256] bool/i32
    const int* use_bg = (const int*)d_in[3];                      // scalar

    float* C = (float*)d_out;  // 32*256*4096
    float* rows_out = C + (size_t)BS * QN * NTGT;
    float* cols_out = rows_out + BS * TN;

    int* flag = (int*)d_ws;
    const size_t ct_off = 4096;
    const size_t ct_bytes = (size_t)BS * TN * QN * sizeof(float);  // 4 MB
    const bool useCT = ws_size >= ct_off + ct_bytes;
    float* CT = useCT ? (float*)((char*)d_ws + ct_off) : nullptr;

    detect_mask_layout<<<1, 256, 0, stream>>>(mask_b, flag);
    compute_C_kernel<<<BS * QN, 256, 0, stream>>>(logits, labels, mask_b, use_bg, flag, C);
    if (useCT) {
        dim3 tg(BS, QN / 64);
        transpose_kernel<<<tg, 256, 0, stream>>>(C, CT);
    }
    lsa_kernel<<<BS, 64, 0, stream>>>(C, CT, rows_out, cols_out);
}

// Round 4
// 1151.795 us; speedup vs baseline: 1.9016x; 1.5255x over previous
//
#include <hip/hip_runtime.h>
#include <hip/hip_bf16.h>
#include <math.h>

#define BS 32
#define QN 256
#define TN 128
#define NCLS 2048
#define NTGT (BS * TN)  // 4096

// ---------------------------------------------------------------------------
// Detect whether agent_mask is stored as 1-byte bools or 4-byte int32.
// ---------------------------------------------------------------------------
__global__ void detect_mask_layout(const unsigned char* __restrict__ m, int* flag) {
    __shared__ int found;
    if (threadIdx.x == 0) found = 0;
    __syncthreads();
    int local = 0;
    for (int i = threadIdx.x; i < BS * QN; i += blockDim.x) {
        if ((i & 3) != 0 && m[i] != 0) local = 1;
    }
    if (local) atomicOr(&found, 1);
    __syncthreads();
    if (threadIdx.x == 0) *flag = found;  // 1 = byte layout, 0 = int32 layout
}

// ---------------------------------------------------------------------------
// C[b,q,jj] = -(softmax(logits[b,q,:])[labels_flat[jj]]), zeroed if masked.
// ---------------------------------------------------------------------------
__global__ __launch_bounds__(256) void compute_C_kernel(
    const float* __restrict__ logits, const int* __restrict__ labels,
    const unsigned char* __restrict__ mask_b, const int* __restrict__ use_bg,
    const int* __restrict__ layout_flag, float* __restrict__ C) {
    __shared__ float prob_sh[NCLS];
    __shared__ int lab_sh[NTGT];
    __shared__ float red[4];

    const int tid = threadIdx.x;
    const int bq = blockIdx.x;  // b*QN + q
    const float* row = logits + (size_t)bq * NCLS;

    for (int k = tid; k < NTGT; k += 256) lab_sh[k] = labels[k];

    float x[8];
    float m = -INFINITY;
#pragma unroll
    for (int k = 0; k < 8; k++) {
        x[k] = row[tid + k * 256];
        m = fmaxf(m, x[k]);
    }
#pragma unroll
    for (int off = 32; off >= 1; off >>= 1) m = fmaxf(m, __shfl_xor(m, off));
    if ((tid & 63) == 0) red[tid >> 6] = m;
    __syncthreads();
    m = fmaxf(fmaxf(red[0], red[1]), fmaxf(red[2], red[3]));
    __syncthreads();

    float e[8];
    float s = 0.f;
#pragma unroll
    for (int k = 0; k < 8; k++) {
        e[k] = expf(x[k] - m);
        s += e[k];
    }
#pragma unroll
    for (int off = 32; off >= 1; off >>= 1) s += __shfl_xor(s, off);
    if ((tid & 63) == 0) red[tid >> 6] = s;
    __syncthreads();
    s = ((red[0] + red[1]) + red[2]) + red[3];

#pragma unroll
    for (int k = 0; k < 8; k++) prob_sh[tid + k * 256] = e[k] / s;

    const int ub = *use_bg;
    int am;
    if (*layout_flag)
        am = mask_b[bq];
    else
        am = ((const int*)mask_b)[bq];
    const bool zero_row = (ub == 0) && (am == 0);
    __syncthreads();

    float* Crow = C + (size_t)bq * NTGT;
#pragma unroll
    for (int k = 0; k < 16; k++) {
        const int jj = tid + k * 256;
        Crow[jj] = zero_row ? 0.0f : -prob_sh[lab_sh[jj]];
    }
}

// ---------------------------------------------------------------------------
// Transpose block-diagonal part of C into CT[b][i][q].
// ---------------------------------------------------------------------------
__global__ __launch_bounds__(256) void transpose_kernel(const float* __restrict__ C,
                                                        float* __restrict__ CT) {
    __shared__ float tile[TN][65];
    const int b = blockIdx.x;
    const int q0 = blockIdx.y * 64;
    const int tid = threadIdx.x;

    const float* src = C + (size_t)(b * QN + q0) * NTGT + b * TN;
#pragma unroll
    for (int it = 0; it < 32; it++) {
        const int idx = tid + it * 256;
        const int ql = idx >> 7;
        const int i = idx & 127;
        tile[i][ql] = src[(size_t)ql * NTGT + i];
    }
    __syncthreads();
    float* dst = CT + (size_t)b * TN * QN + q0;
#pragma unroll
    for (int it = 0; it < 32; it++) {
        const int idx = tid + it * 256;
        const int i = idx >> 6;
        const int ql = idx & 63;
        dst[(size_t)i * QN + ql] = tile[i][ql];
    }
}

// ---------------------------------------------------------------------------
// Cross-lane helpers.
// ---------------------------------------------------------------------------
template <int CTRL>
__device__ __forceinline__ double dpp_mov_f64(double x) {
    union { double d; int i[2]; } a, r;
    a.d = x;
    r.i[0] = __builtin_amdgcn_update_dpp(0, a.i[0], CTRL, 0xF, 0xF, true);
    r.i[1] = __builtin_amdgcn_update_dpp(0, a.i[1], CTRL, 0xF, 0xF, true);
    return r.d;
}
__device__ __forceinline__ double read_lane_f64(double x, int srclane) {
    union { double d; int i[2]; } a, r;
    a.d = x;
    r.i[0] = __builtin_amdgcn_readlane(a.i[0], srclane);
    r.i[1] = __builtin_amdgcn_readlane(a.i[1], srclane);
    return r.d;
}

#define QUAD_XOR1 0xB1   // quad_perm(1,0,3,2)
#define QUAD_XOR2 0x4E   // quad_perm(2,3,0,1)
#define ROW_ROR4  0x124  // row_ror:4
#define ROW_ROR8  0x128  // row_ror:8

// ---------------------------------------------------------------------------
// Jonker-Volgenant, exact replica of reference _lsa() on the transposed
// problem (nr=TN=128 rows=targets, nc=QN=256 cols=queries). One wave/batch;
// lane owns columns 4l..4l+3 (d, v, SC, path in REGISTERS) and rows 2l,2l+1
// (u/du/SR mirrors in registers). Only per-pop LDS op: cost-row ds_read_b128
// + broadcast u read. Argmin = v_min_f64 DPP tree + readlanes + eq-ballot +
// scalar first-bit. Tie fast path: if no d improved, the min and tied set
// are unchanged -> next pop = next bit of the saved ballot (skips reduce);
// identical to scipy's recomputed argmin.
// ---------------------------------------------------------------------------
__global__ __launch_bounds__(64) void lsa_kernel(const float* __restrict__ C,
                                                 const float* __restrict__ CT,
                                                 float* __restrict__ rows_out,
                                                 float* __restrict__ cols_out) {
    const int b = blockIdx.x;
    const int lane = threadIdx.x;  // 0..63
    const int j0 = lane * 4;

    __shared__ float cost_sh[TN * QN];  // [i][q], 128 KB
    __shared__ double u_sh[TN];
    __shared__ int path_sh[QN];     // interleaved: [slot*64 + owner]
    __shared__ int row4col_sh[QN];
    __shared__ int col4row_sh[TN];

    u_sh[lane] = 0.0;
    u_sh[lane + 64] = 0.0;
    col4row_sh[lane] = -1;
    col4row_sh[lane + 64] = -1;
#pragma unroll
    for (int t = 0; t < 4; t++) row4col_sh[lane + 64 * t] = -1;

    double v0 = 0.0, v1 = 0.0, v2 = 0.0, v3 = 0.0;  // col duals (owned cols)
    double u0 = 0.0, u1 = 0.0;                      // row duals (owned rows)

    if (CT) {
        const float4* src = (const float4*)(CT + (size_t)b * TN * QN);
        float4* dst = (float4*)cost_sh;
#pragma unroll 8
        for (int it = 0; it < TN * QN / 4 / 64; it++) {
            const int idx = it * 64 + lane;
            dst[idx] = src[idx];
        }
    } else {
        // fallback: scattered gather straight from C (32-way write conflicts,
        // one-time staging cost only)
        const float* cbsrc = C + (size_t)b * QN * NTGT + b * TN;
        for (int it = 0; it < 512; it++) {
            const int j = it >> 1;
            const int i = lane + 64 * (it & 1);
            cost_sh[i * QN + j] = cbsrc[(size_t)j * NTGT + i];
        }
    }
    __syncthreads();

    for (int cur = 0; cur < TN; cur++) {
        double dv0 = INFINITY, dv1 = INFINITY, dv2 = INFINITY, dv3 = INFINITY;
        double dm0 = INFINITY, dm1 = INFINITY, dm2 = INFINITY, dm3 = INFINITY;
        double du0 = 0.0, du1 = 0.0;
        int sc = 0, sr = 0;
        int p0 = 0, p1 = 0, p2 = 0, p3 = 0;
        const int4 rcv = *(const int4*)&row4col_sh[j0];  // row4col mirror
        if (lane == (cur >> 1)) sr = 1 << (cur & 1);     // SR[cur]=1

        int i = cur;
        double m_d = 0.0;
        bool need_reduce = true;
        unsigned long long B0 = 0, B1 = 0, B2 = 0, B3 = 0;
        int sink;

        while (true) {
            const float4 cc = *(const float4*)(cost_sh + i * QN + j0);
            const double ui = u_sh[i];  // broadcast read

            // numpy order: ((minVal + cost) - u[i]) - v[j]; strict r < d
            const double ca0 = ((m_d + (double)cc.x) - ui) - v0;
            const double ca1 = ((m_d + (double)cc.y) - ui) - v1;
            const double ca2 = ((m_d + (double)cc.z) - ui) - v2;
            const double ca3 = ((m_d + (double)cc.w) - ui) - v3;
            const bool i0 = !(sc & 1) && (ca0 < dv0);
            const bool i1 = !(sc & 2) && (ca1 < dv1);
            const bool i2 = !(sc & 4) && (ca2 < dv2);
            const bool i3 = !(sc & 8) && (ca3 < dv3);
            const unsigned long long anyI =
                __ballot(i0) | __ballot(i1) | __ballot(i2) | __ballot(i3);
            if (i0) { dv0 = ca0; dm0 = ca0; p0 = i; }
            if (i1) { dv1 = ca1; dm1 = ca1; p1 = i; }
            if (i2) { dv2 = ca2; dm2 = ca2; p2 = i; }
            if (i3) { dv3 = ca3; dm3 = ca3; p3 = i; }

            if (anyI != 0ull || need_reduce) {
                // full argmin: f64 min tree (4 DPP row stages + readlane finish)
                double lm = fmin(fmin(dm0, dm1), fmin(dm2, dm3));
                lm = fmin(lm, dpp_mov_f64<QUAD_XOR1>(lm));
                lm = fmin(lm, dpp_mov_f64<QUAD_XOR2>(lm));
                lm = fmin(lm, dpp_mov_f64<ROW_ROR4>(lm));
                lm = fmin(lm, dpp_mov_f64<ROW_ROR8>(lm));
                const double r0 = read_lane_f64(lm, 0);
                const double r1 = read_lane_f64(lm, 16);
                const double r2 = read_lane_f64(lm, 32);
                const double r3 = read_lane_f64(lm, 48);
                m_d = fmin(fmin(r0, r1), fmin(r2, r3));
                // tied set (dm=INF for SC'd -> excluded automatically)
                B0 = __ballot(dm0 == m_d);
                B1 = __ballot(dm1 == m_d);
                B2 = __ballot(dm2 == m_d);
                B3 = __ballot(dm3 == m_d);
            }

            // first-min index among tied set (scalar)
            int jmin = 0x7fffffff;
            if (B0) { const int c = ((__ffsll((long long)B0) - 1) << 2) + 0; jmin = c < jmin ? c : jmin; }
            if (B1) { const int c = ((__ffsll((long long)B1) - 1) << 2) + 1; jmin = c < jmin ? c : jmin; }
            if (B2) { const int c = ((__ffsll((long long)B2) - 1) << 2) + 2; jmin = c < jmin ? c : jmin; }
            if (B3) { const int c = ((__ffsll((long long)B3) - 1) << 2) + 3; jmin = c < jmin ? c : jmin; }
            const int owner = jmin >> 2;
            const int slot = jmin & 3;
            const unsigned long long bit = 1ull << owner;
            if (slot == 0) B0 &= ~bit;
            else if (slot == 1) B1 &= ~bit;
            else if (slot == 2) B2 &= ~bit;
            else B3 &= ~bit;

            if (lane == owner) {  // mark SC, freeze dm
                sc |= 1 << slot;
                if (slot == 0) dm0 = INFINITY;
                else if (slot == 1) dm1 = INFINITY;
                else if (slot == 2) dm2 = INFINITY;
                else dm3 = INFINITY;
            }

            // krc = row4col[jmin] via register mirror + readlane
            const int sa = (slot & 1) ? rcv.y : rcv.x;
            const int sb = (slot & 1) ? rcv.w : rcv.z;
            const int rcsel = (slot & 2) ? sb : sa;
            const int krc = __builtin_amdgcn_readlane(rcsel, owner);
            if (krc < 0) { sink = jmin; break; }

            // SR/du row mirrors
            if (lane == (krc >> 1)) {
                if (krc & 1) { du1 = m_d; sr |= 2; }
                else { du0 = m_d; sr |= 1; }
            }
            i = krc;
            need_reduce = ((B0 | B1 | B2 | B3) == 0ull);
        }

        // ---- round end ----
        // publish path regs (conflict-free interleaved layout)
        path_sh[lane] = p0;
        path_sh[lane + 64] = p1;
        path_sh[lane + 128] = p2;
        path_sh[lane + 192] = p3;
        // dual updates (scipy _lsap_body); dv/du frozen at selection time
        if (sc & 1) v0 -= m_d - dv0;
        if (sc & 2) v1 -= m_d - dv1;
        if (sc & 4) v2 -= m_d - dv2;
        if (sc & 8) v3 -= m_d - dv3;
        if (sr & 1) u0 += (2 * lane == cur) ? m_d : (m_d - du0);
        if (sr & 2) u1 += (2 * lane + 1 == cur) ? m_d : (m_d - du1);
        u_sh[2 * lane] = u0;
        u_sh[2 * lane + 1] = u1;
        __syncthreads();  // path/u visible

        if (lane == 0) {  // augment along shortest path
            int j = sink;
            while (true) {
                const int pi = path_sh[(j & 3) * 64 + (j >> 2)];
                row4col_sh[j] = pi;
                const int nj = col4row_sh[pi];
                col4row_sh[pi] = j;
                j = nj;
                if (pi == cur) break;
            }
        }
        __syncthreads();  // row4col/col4row visible for next round
    }

    // transposed output: rank by col4row value (values distinct)
#pragma unroll
    for (int t = 0; t < 2; t++) {
        const int ii = lane + 64 * t;
        const int myv = col4row_sh[ii];
        int rank = 0;
        for (int t2 = 0; t2 < TN; t2++) rank += (col4row_sh[t2] < myv) ? 1 : 0;
        rows_out[b * TN + rank] = (float)myv;
        cols_out[b * TN + rank] = (float)ii;
    }
}

extern "C" void kernel_launch(void* const* d_in, const int* in_sizes, int n_in,
                              void* d_out, int out_size, void* d_ws, size_t ws_size,
                              hipStream_t stream) {
    const float* logits = (const float*)d_in[0];                  // [32,256,2048] f32
    const int* labels = (const int*)d_in[1];                      // [32,128] i32
    const unsigned char* mask_b = (const unsigned char*)d_in[2];  // [32,256] bool/i32
    const int* use_bg = (const int*)d_in[3];                      // scalar

    float* C = (float*)d_out;  // 32*256*4096
    float* rows_out = C + (size_t)BS * QN * NTGT;
    float* cols_out = rows_out + BS * TN;

    int* flag = (int*)d_ws;
    const size_t ct_off = 4096;
    const size_t ct_bytes = (size_t)BS * TN * QN * sizeof(float);  // 4 MB
    const bool useCT = ws_size >= ct_off + ct_bytes;
    float* CT = useCT ? (float*)((char*)d_ws + ct_off) : nullptr;

    detect_mask_layout<<<1, 256, 0, stream>>>(mask_b, flag);
    compute_C_kernel<<<BS * QN, 256, 0, stream>>>(logits, labels, mask_b, use_bg, flag, C);
    if (useCT) {
        dim3 tg(BS, QN / 64);
        transpose_kernel<<<tg, 256, 0, stream>>>(C, CT);
    }
    lsa_kernel<<<BS, 64, 0, stream>>>(C, CT, rows_out, cols_out);
}